// Round 4
// baseline (1029.591 us; speedup 1.0000x reference)
//
#include <hip/hip_runtime.h>

typedef __bf16 bf16_t;
typedef bf16_t bf16x8 __attribute__((ext_vector_type(8)));
typedef bf16_t bf16x4 __attribute__((ext_vector_type(4)));
typedef float f32x4 __attribute__((ext_vector_type(4)));

#define BATCH 16384
#define KDIM  1024
#define NCOLS 9216   // [0,3072) ig | [3072,4096) ii | [4096,5120) ih | [5120,8192) hg | [8192,9216) hh

#define BMg 256
#define BNg 256
// K processed as 32 slices of 32 (one LDS half-slot each)

// ---------------- cast f32 -> bf16 ----------------
__global__ __launch_bounds__(256) void cast_f32_bf16(const float* __restrict__ src,
                                                     bf16_t* __restrict__ dst, int n4) {
  int i = blockIdx.x * 256 + threadIdx.x;
  if (i < n4) {
    float4 v = reinterpret_cast<const float4*>(src)[i];
    bf16x4 o;
    o[0] = (bf16_t)v.x; o[1] = (bf16_t)v.y; o[2] = (bf16_t)v.z; o[3] = (bf16_t)v.w;
    reinterpret_cast<bf16x4*>(dst)[i] = o;
  }
}

// ---------------- bias concat ----------------
__global__ __launch_bounds__(256)
void concat_bias(const float* __restrict__ b_ig, const float* __restrict__ b_ii,
                 const float* __restrict__ b_ih, const float* __restrict__ b_hg,
                 const float* __restrict__ b_hh, float* __restrict__ bcat) {
  int i = blockIdx.x * 256 + threadIdx.x;
  if (i >= NCOLS) return;
  float v;
  if      (i < 3072) v = b_ig[i];
  else if (i < 4096) v = b_ii[i - 3072];
  else if (i < 5120) v = b_ih[i - 4096];
  else if (i < 8192) v = b_hg[i - 5120];
  else               v = b_hh[i - 8192];
  bcat[i] = v;
}

// ---------------- GEMM: 256x256 tile, 8 waves (2Mx4N), 16x16x32 MFMA ----------------
// K-slice phases: phase H computes k-slice [H*32,+32) for all 32 per-wave fragments.
// LDS = 4 half-slots x (A 16KB + B 16KB) = 128 KiB; slot H&3 live only during phase H.
// stage(H+3) each phase; steady-state s_waitcnt vmcnt(8) (never 0 except tail).
// Swizzle: 16B chunk (row,k8) stored at chunk' = k8 ^ ((row>>1)&3); inverse applied on
// the global source (global_load_lds writes linearly). Bank-uniform: group =
// 4*(row&1) + chunk' enumerates all 8 groups over any 16 consecutive rows.
__global__ __launch_bounds__(512, 2)
void gemm_preln(const bf16_t* __restrict__ inpb, const bf16_t* __restrict__ hidb,
                const bf16_t* __restrict__ Wcat, const float* __restrict__ bcat,
                bf16_t* __restrict__ preLN, int nbm)
{
  __shared__ alignas(16) bf16_t lds[4 * 16384];   // 128 KiB

  const int tid  = threadIdx.x;
  const int wid  = tid >> 6;
  const int lane = tid & 63;

  // XCD-aware bijective block swizzle
  const int nwg = nbm * (NCOLS / BNg);
  int orig = blockIdx.x;
  int q = nwg >> 3, r = nwg & 7, xcd = orig & 7, idx = orig >> 3;
  int wg = (xcd < r ? xcd * (q + 1) : r * (q + 1) + (xcd - r) * q) + idx;
  const int bm = wg / (NCOLS / BNg);
  const int bn = wg % (NCOLS / BNg);
  const int row0 = bm * BMg, col0 = bn * BNg;
  const bf16_t* __restrict__ act = (col0 < 5120) ? inpb : hidb;
  const bf16_t* __restrict__ wgt = Wcat + (size_t)col0 * KDIM;

  const int wr = wid >> 2;            // 0..1 -> rows wr*128
  const int wc = wid & 3;             // 0..3 -> cols wc*64
  const int fr = lane & 15;
  const int kg = lane >> 4;

  // staging: per thread 2 A-chunks + 2 B-chunks per phase (16B each)
  const bf16_t* gA[2]; const bf16_t* gB[2];
  #pragma unroll
  for (int l = 0; l < 2; ++l) {
    int c = l * 512 + tid;            // chunk in [0,1024)
    int rrow = c >> 2, cp = c & 3;
    int k8 = cp ^ ((rrow >> 1) & 3);  // inverse swizzle on source
    gA[l] = act + (size_t)(row0 + rrow) * KDIM + k8 * 8;
    gB[l] = wgt + (size_t)rrow * KDIM + k8 * 8;
  }

  // ds-read offsets within slot (elems), fixed per lane
  int aoff[8], boff[4];
  #pragma unroll
  for (int m = 0; m < 8; ++m) {
    int rrow = wr * 128 + m * 16 + fr;
    aoff[m] = rrow * 32 + ((kg ^ ((rrow >> 1) & 3)) * 8);
  }
  #pragma unroll
  for (int n = 0; n < 4; ++n) {
    int ccol = wc * 64 + n * 16 + fr;
    boff[n] = 8192 + ccol * 32 + ((kg ^ ((ccol >> 1) & 3)) * 8);
  }

  f32x4 acc[8][4] = {};

  auto stage = [&](int H) {
    bf16_t* base = lds + (H & 3) * 16384;
    #pragma unroll
    for (int l = 0; l < 2; ++l) {
      __builtin_amdgcn_global_load_lds(
        (const __attribute__((address_space(1))) unsigned int*)(gA[l] + H * 32),
        (__attribute__((address_space(3))) unsigned int*)(base + (l * 512 + wid * 64) * 8),
        16, 0, 0);
      __builtin_amdgcn_global_load_lds(
        (const __attribute__((address_space(1))) unsigned int*)(gB[l] + H * 32),
        (__attribute__((address_space(3))) unsigned int*)(base + 8192 + (l * 512 + wid * 64) * 8),
        16, 0, 0);
    }
  };

  // prologue: halves 0,1,2 in flight (12 loads); certify half 0
  stage(0); stage(1); stage(2);
  asm volatile("s_waitcnt vmcnt(8)" ::: "memory");
  __builtin_amdgcn_s_barrier();
  asm volatile("" ::: "memory");

  for (int H = 0; H < 32; ++H) {
    if (H + 3 < 32) stage(H + 3);     // slot (H+3)&3 == (H-1)&3, freed at prev barrier

    const bf16_t* sl = lds + (H & 3) * 16384;
    bf16x8 a[8], b[4];
    #pragma unroll
    for (int m = 0; m < 8; ++m) a[m] = *(const bf16x8*)(sl + aoff[m]);
    #pragma unroll
    for (int n = 0; n < 4; ++n) b[n] = *(const bf16x8*)(sl + boff[n]);

    __builtin_amdgcn_s_setprio(1);
    #pragma unroll
    for (int m = 0; m < 8; ++m)
      #pragma unroll
      for (int n = 0; n < 4; ++n)
        acc[m][n] = __builtin_amdgcn_mfma_f32_16x16x32_bf16(a[m], b[n], acc[m][n], 0, 0, 0);
    __builtin_amdgcn_s_setprio(0);

    if (H < 31) {
      // certify half H+1 (issued at phase H-2): drain to (#loads issued at H-1 and H)
      if (H <= 28)      asm volatile("s_waitcnt vmcnt(8)" ::: "memory");
      else if (H == 29) asm volatile("s_waitcnt vmcnt(4)" ::: "memory");
      else              asm volatile("s_waitcnt vmcnt(0)" ::: "memory");
      __builtin_amdgcn_s_barrier();
      asm volatile("" ::: "memory");
    }
  }

  // epilogue: bias + bf16 store. C/D 16x16: col=lane&15, row=(lane>>4)*4+j (verified R2)
  #pragma unroll
  for (int n = 0; n < 4; ++n) {
    const int col = col0 + wc * 64 + n * 16 + fr;
    const float bias = bcat[col];
    #pragma unroll
    for (int m = 0; m < 8; ++m) {
      const int rbase = row0 + wr * 128 + m * 16 + kg * 4;
      #pragma unroll
      for (int j = 0; j < 4; ++j)
        preLN[(size_t)(rbase + j) * NCOLS + col] = (bf16_t)(acc[m][n][j] + bias);
    }
  }
}

// ---------------- fused LN + gates + combine: one wave per row, register-resident ----------------
__global__ __launch_bounds__(256)
void ln_combine(const bf16_t* __restrict__ preLN, const float* __restrict__ hidden,
                const float* __restrict__ g_ig, const float* __restrict__ be_ig,
                const float* __restrict__ g_hg, const float* __restrict__ be_hg,
                const float* __restrict__ g_ii, const float* __restrict__ be_ii,
                const float* __restrict__ g_ih, const float* __restrict__ be_ih,
                const float* __restrict__ g_hh, const float* __restrict__ be_hh,
                float* __restrict__ out)
{
  const int ln = threadIdx.x & 63;
  const int wv = threadIdx.x >> 6;
  const int row = blockIdx.x * 4 + wv;
  const bf16_t* __restrict__ src = preLN + (size_t)row * NCOLS;

  // 18 x 16B per lane: unit u = j*64+ln covers elems [u*8, u*8+8)
  uint4 u[18];
  #pragma unroll
  for (int j = 0; j < 18; ++j)
    u[j] = *(const uint4*)(src + ((size_t)(j * 64 + ln)) * 8);

  // per-segment stats (segment per j is compile-time)
  float s1[5] = {0.f,0.f,0.f,0.f,0.f}, s2[5] = {0.f,0.f,0.f,0.f,0.f};
  #pragma unroll
  for (int j = 0; j < 18; ++j) {
    const int sg = (j < 6) ? 0 : (j < 8) ? 1 : (j < 10) ? 2 : (j < 16) ? 3 : 4;
    const unsigned* pw = (const unsigned*)&u[j];
    #pragma unroll
    for (int t = 0; t < 4; ++t) {
      float lo = __uint_as_float(pw[t] << 16);
      float hi = __uint_as_float(pw[t] & 0xFFFF0000u);
      s1[sg] += lo + hi;
      s2[sg] += lo * lo + hi * hi;
    }
  }
  #pragma unroll
  for (int s = 0; s < 5; ++s)
    #pragma unroll
    for (int off = 32; off; off >>= 1) {
      s1[s] += __shfl_xor(s1[s], off);
      s2[s] += __shfl_xor(s2[s], off);
    }
  const float nn[5] = {3072.f, 1024.f, 1024.f, 3072.f, 1024.f};
  float mu[5], rs[5];
  #pragma unroll
  for (int s = 0; s < 5; ++s) {
    mu[s] = s1[s] / nn[s];
    rs[s] = rsqrtf(s2[s] / nn[s] - mu[s] * mu[s] + 1e-5f);
  }

  const float* __restrict__ hrow = hidden + (size_t)row * 1024;
  float* __restrict__ orow = out + (size_t)row * 1024;

  // lane ln owns cols [ln*8, ln*8+8) (half=0, even j) and [512+ln*8, +8) (half=1, odd j)
  #pragma unroll
  for (int half = 0; half < 2; ++half) {
    const int cb = half * 512 + ln * 8;
    #pragma unroll
    for (int i = 0; i < 8; ++i) {
      const int c = cb + i;
      auto getf = [&](int j) {
        const unsigned* pw = (const unsigned*)&u[j];
        unsigned w = pw[i >> 1];
        return (i & 1) ? __uint_as_float(w & 0xFFFF0000u) : __uint_as_float(w << 16);
      };
      float x_igr = getf(0  + half);
      float x_igz = getf(2  + half);
      float x_igg = getf(4  + half);
      float x_ii  = getf(6  + half);
      float x_ih  = getf(8  + half);
      float x_hgr = getf(10 + half);
      float x_hgz = getf(12 + half);
      float x_hgg = getf(14 + half);
      float x_hh  = getf(16 + half);

      float pr = (x_igr - mu[0]) * rs[0] * g_ig[c]        + be_ig[c]
               + (x_hgr - mu[3]) * rs[3] * g_hg[c]        + be_hg[c];
      float pz = (x_igz - mu[0]) * rs[0] * g_ig[c + 1024] + be_ig[c + 1024]
               + (x_hgz - mu[3]) * rs[3] * g_hg[c + 1024] + be_hg[c + 1024];
      float pg = (x_igg - mu[0]) * rs[0] * g_ig[c + 2048] + be_ig[c + 2048]
               + (x_hgg - mu[3]) * rs[3] * g_hg[c + 2048] + be_hg[c + 2048];

      float rr = 1.f / (1.f + __expf(-pr));
      float zz = 1.f / (1.f + __expf(-pz));
      float gg = 1.f / (1.f + __expf(-pg));

      float Hx = (x_ii - mu[1]) * rs[1] * g_ii[c] + be_ii[c];
      float xh = (x_ih - mu[2]) * rs[2] * g_ih[c] + be_ih[c];
      float hh = (x_hh - mu[4]) * rs[4] * g_hh[c] + be_hh[c];

      float hm = tanhf((1.f - rr) * xh + rr * hh);
      float h  = hrow[c];
      orow[c] = ((1.f - zz) * h + zz * hm) * (1.f - gg) + gg * Hx;
    }
  }
}

extern "C" void kernel_launch(void* const* d_in, const int* in_sizes, int n_in,
                              void* d_out, int out_size, void* d_ws, size_t ws_size,
                              hipStream_t stream) {
  const float* inp      = (const float*)d_in[0];
  const float* hidden   = (const float*)d_in[1];
  const float* W_i2gate = (const float*)d_in[2];
  const float* b_i2gate = (const float*)d_in[3];
  const float* W_h2gate = (const float*)d_in[4];
  const float* b_h2gate = (const float*)d_in[5];
  const float* W_i2i    = (const float*)d_in[6];
  const float* b_i2i    = (const float*)d_in[7];
  const float* W_i2h    = (const float*)d_in[8];
  const float* b_i2h    = (const float*)d_in[9];
  const float* W_h2h    = (const float*)d_in[10];
  const float* b_h2h    = (const float*)d_in[11];
  const float* g_ig  = (const float*)d_in[12];
  const float* be_ig = (const float*)d_in[13];
  const float* g_hg  = (const float*)d_in[14];
  const float* be_hg = (const float*)d_in[15];
  const float* g_ii  = (const float*)d_in[16];
  const float* be_ii = (const float*)d_in[17];
  const float* g_ih  = (const float*)d_in[18];
  const float* be_ih = (const float*)d_in[19];
  const float* g_hh  = (const float*)d_in[20];
  const float* be_hh = (const float*)d_in[21];
  float* out = (float*)d_out;

  const size_t WCAT_B  = (size_t)NCOLS * KDIM * 2;     // 18,874,368
  const size_t BCAT_B  = (size_t)NCOLS * 4;            // 36,864
  const size_t FIXED_B = WCAT_B + BCAT_B;
  const size_t PER_ROW = 2048 + 2048 + 18432;          // 22,528

  if (ws_size < FIXED_B + PER_ROW * 256) return;       // visible fail, no OOB

  char* ws = (char*)d_ws;
  bf16_t* Wcat = (bf16_t*)ws;
  float*  bcat = (float*)(ws + WCAT_B);
  char*   dyn  = ws + FIXED_B;

  size_t max_rows = (ws_size - FIXED_B) / PER_ROW;
  int chunk = (int)((max_rows / 256) * 256);
  if (chunk > BATCH) chunk = BATCH;

  bf16_t* inpb  = (bf16_t*)dyn;
  bf16_t* hidb  = (bf16_t*)(dyn + (size_t)chunk * 2048);
  bf16_t* preLN = (bf16_t*)(dyn + (size_t)chunk * 4096);

  {
    int n4g = 3072 * 1024 / 4, n4s = 1024 * 1024 / 4;
    cast_f32_bf16<<<(n4g + 255) / 256, 256, 0, stream>>>(W_i2gate, Wcat, n4g);
    cast_f32_bf16<<<(n4s + 255) / 256, 256, 0, stream>>>(W_i2i, Wcat + 3072 * 1024, n4s);
    cast_f32_bf16<<<(n4s + 255) / 256, 256, 0, stream>>>(W_i2h, Wcat + 4096 * 1024, n4s);
    cast_f32_bf16<<<(n4g + 255) / 256, 256, 0, stream>>>(W_h2gate, Wcat + 5120 * 1024, n4g);
    cast_f32_bf16<<<(n4s + 255) / 256, 256, 0, stream>>>(W_h2h, Wcat + 8192 * 1024, n4s);
    concat_bias<<<(NCOLS + 255) / 256, 256, 0, stream>>>(b_i2gate, b_i2i, b_i2h,
                                                         b_h2gate, b_h2h, bcat);
  }

  for (int r0 = 0; r0 < BATCH; r0 += chunk) {
    int cr = BATCH - r0;
    if (cr > chunk) cr = chunk;
    int n4 = cr * KDIM / 4;
    cast_f32_bf16<<<(n4 + 255) / 256, 256, 0, stream>>>(inp + (size_t)r0 * KDIM, inpb, n4);
    cast_f32_bf16<<<(n4 + 255) / 256, 256, 0, stream>>>(hidden + (size_t)r0 * KDIM, hidb, n4);

    int nbm = cr / BMg;
    int nwg = nbm * (NCOLS / BNg);
    gemm_preln<<<nwg, 512, 0, stream>>>(inpb, hidb, Wcat, bcat, preLN, nbm);

    ln_combine<<<cr / 4, 256, 0, stream>>>(preLN, hidden + (size_t)r0 * KDIM,
                                           g_ig, be_ig, g_hg, be_hg,
                                           g_ii, be_ii, g_ih, be_ih, g_hh, be_hh,
                                           out + (size_t)r0 * KDIM);
  }
}

// Round 5
// 838.466 us; speedup vs baseline: 1.2279x; 1.2279x over previous
//
#include <hip/hip_runtime.h>

typedef __bf16 bf16_t;
typedef bf16_t bf16x8 __attribute__((ext_vector_type(8)));
typedef bf16_t bf16x4 __attribute__((ext_vector_type(4)));
typedef float f32x4 __attribute__((ext_vector_type(4)));
typedef float f32x8_t __attribute__((ext_vector_type(8)));

#define BATCH 16384
#define KDIM  1024
#define NCOLS 9216   // [0,3072) ig | [3072,4096) ii | [4096,5120) ih | [5120,8192) hg | [8192,9216) hh

#define BM 128
#define BN 128
#define BK 32

// ---------------- cast f32 -> bf16 ----------------
__global__ __launch_bounds__(256) void cast_f32_bf16(const float* __restrict__ src,
                                                     bf16_t* __restrict__ dst, int n4) {
  int i = blockIdx.x * 256 + threadIdx.x;
  if (i < n4) {
    float4 v = reinterpret_cast<const float4*>(src)[i];
    bf16x4 o;
    o[0] = (bf16_t)v.x; o[1] = (bf16_t)v.y; o[2] = (bf16_t)v.z; o[3] = (bf16_t)v.w;
    reinterpret_cast<bf16x4*>(dst)[i] = o;
  }
}

// ---------------- bias concat ----------------
__global__ __launch_bounds__(256)
void concat_bias(const float* __restrict__ b_ig, const float* __restrict__ b_ii,
                 const float* __restrict__ b_ih, const float* __restrict__ b_hg,
                 const float* __restrict__ b_hh, float* __restrict__ bcat) {
  int i = blockIdx.x * 256 + threadIdx.x;
  if (i >= NCOLS) return;
  float v;
  if      (i < 3072) v = b_ig[i];
  else if (i < 4096) v = b_ii[i - 3072];
  else if (i < 5120) v = b_ih[i - 4096];
  else if (i < 8192) v = b_hg[i - 5120];
  else               v = b_hh[i - 8192];
  bcat[i] = v;
}

// ---------------- GEMM (R2-proven m97 structure, 330 us) + per-row partial stats ----------------
__global__ __launch_bounds__(256)
void gemm_preln(const bf16_t* __restrict__ inpb, const bf16_t* __restrict__ hidb,
                const bf16_t* __restrict__ Wcat, const float* __restrict__ bcat,
                bf16_t* __restrict__ preLN,
                float* __restrict__ part1, float* __restrict__ part2, int crows)
{
  __shared__ alignas(16) bf16_t As[2][BM * BK];
  __shared__ alignas(16) bf16_t Bs[2][BN * BK];
  const int tid  = threadIdx.x;
  const int wid  = tid >> 6;
  const int lane = tid & 63;
  const int row0 = blockIdx.x * BM;
  const int col0 = blockIdx.y * BN;
  const bf16_t* __restrict__ act = (col0 < 5120) ? inpb : hidb;
  const bf16_t* __restrict__ wgt = Wcat + (size_t)col0 * KDIM;

  f32x4 acc[4][4] = {};

  const int wr = wid >> 1, wc = wid & 1;
  const int fr = lane & 15;
  const int kg = lane >> 4;

  auto stage = [&](int buf, int kt) {
    const int k0 = kt * BK;
    #pragma unroll
    for (int c = 0; c < 2; ++c) {
      const int e = c * 2048 + tid * 8;
      const int r = e >> 5, kk = e & 31;
      const bf16_t* ga = act + (size_t)(row0 + r) * KDIM + (k0 + kk);
      const bf16_t* gb = wgt + (size_t)r * KDIM + (k0 + kk);
      __builtin_amdgcn_global_load_lds(
          (const __attribute__((address_space(1))) unsigned int*)ga,
          (__attribute__((address_space(3))) unsigned int*)&As[buf][c * 2048 + wid * 512],
          16, 0, 0);
      __builtin_amdgcn_global_load_lds(
          (const __attribute__((address_space(1))) unsigned int*)gb,
          (__attribute__((address_space(3))) unsigned int*)&Bs[buf][c * 2048 + wid * 512],
          16, 0, 0);
    }
  };

  auto compute = [&](int buf) {
    bf16x8 a[4], b[4];
    #pragma unroll
    for (int m = 0; m < 4; ++m)
      a[m] = *(const bf16x8*)&As[buf][(wr * 64 + m * 16 + fr) * BK + kg * 8];
    #pragma unroll
    for (int n = 0; n < 4; ++n)
      b[n] = *(const bf16x8*)&Bs[buf][(wc * 64 + n * 16 + fr) * BK + kg * 8];
    #pragma unroll
    for (int m = 0; m < 4; ++m)
      #pragma unroll
      for (int n = 0; n < 4; ++n)
        acc[m][n] = __builtin_amdgcn_mfma_f32_16x16x32_bf16(a[m], b[n], acc[m][n], 0, 0, 0);
  };

  stage(0, 0);
  __syncthreads();
  int cur = 0;
  const int NT = KDIM / BK;
  for (int t = 0; t < NT; ++t) {
    if (t + 1 < NT) stage(cur ^ 1, t + 1);
    compute(cur);
    __syncthreads();
    cur ^= 1;
  }

  // epilogue: bias + bf16 store + per-row partial sums over this wave's 64-col slice.
  // C/D 16x16 layout: col=lane&15, row=(lane>>4)*4+j (verified R2).
  float s1r[4][4] = {};  // [m][j]
  float s2r[4][4] = {};
  const int orow = row0 + wr * 64;
  const int ocol = col0 + wc * 64;
  #pragma unroll
  for (int n = 0; n < 4; ++n) {
    const int col = ocol + n * 16 + fr;
    const float bias = bcat[col];
    #pragma unroll
    for (int m = 0; m < 4; ++m) {
      const int rbase = orow + m * 16 + kg * 4;
      #pragma unroll
      for (int j = 0; j < 4; ++j) {
        bf16_t h = (bf16_t)(acc[m][n][j] + bias);
        preLN[(size_t)(rbase + j) * NCOLS + col] = h;
        float vr = (float)h;
        s1r[m][j] += vr;
        s2r[m][j] += vr * vr;
      }
    }
  }
  // reduce across the 16 fr-lanes (xor masks 1..8 stay within the kg group)
  const int cb = (col0 >> 6) + wc;              // 64-col block id, 0..143
  #pragma unroll
  for (int m = 0; m < 4; ++m)
    #pragma unroll
    for (int j = 0; j < 4; ++j) {
      float a = s1r[m][j], b = s2r[m][j];
      #pragma unroll
      for (int off = 1; off < 16; off <<= 1) {
        a += __shfl_xor(a, off);
        b += __shfl_xor(b, off);
      }
      if (fr == 0) {
        const int row = orow + m * 16 + kg * 4 + j;
        part1[(size_t)cb * crows + row] = a;
        part2[(size_t)cb * crows + row] = b;
      }
    }
}

// ---------------- per-row stats from col-block partials ----------------
__global__ __launch_bounds__(256)
void stat_reduce(const float* __restrict__ part1, const float* __restrict__ part2,
                 float* __restrict__ stats, int crows) {
  int row = blockIdx.x * 256 + threadIdx.x;
  if (row >= crows) return;
  const int lo[5] = {0, 48, 64, 80, 128};
  const int hi[5] = {48, 64, 80, 128, 144};
  const float nn[5] = {3072.f, 1024.f, 1024.f, 3072.f, 1024.f};
  #pragma unroll
  for (int s = 0; s < 5; ++s) {
    float t1 = 0.f, t2 = 0.f;
    for (int c = lo[s]; c < hi[s]; ++c) {
      t1 += part1[(size_t)c * crows + row];
      t2 += part2[(size_t)c * crows + row];
    }
    float mu = t1 / nn[s];
    stats[(size_t)row * 10 + s] = mu;
    stats[(size_t)row * 10 + 5 + s] = rsqrtf(t2 / nn[s] - mu * mu + 1e-5f);
  }
}

// ---------------- elementwise combine: 8 cols/thread, fully coalesced ----------------
__device__ __forceinline__ f32x8_t ld8f(const float* __restrict__ p) {
  f32x8_t r;
  *(float4*)&r       = *(const float4*)p;
  *((float4*)&r + 1) = *(const float4*)(p + 4);
  return r;
}
__device__ __forceinline__ f32x8_t cvt8(bf16x8 v) {
  f32x8_t r;
  #pragma unroll
  for (int i = 0; i < 8; ++i) r[i] = (float)v[i];
  return r;
}

__global__ __launch_bounds__(256)
void combine(const bf16_t* __restrict__ preLN, const float* __restrict__ stats,
             const float* __restrict__ hidden,
             const float* __restrict__ g_ig, const float* __restrict__ be_ig,
             const float* __restrict__ g_hg, const float* __restrict__ be_hg,
             const float* __restrict__ g_ii, const float* __restrict__ be_ii,
             const float* __restrict__ g_ih, const float* __restrict__ be_ih,
             const float* __restrict__ g_hh, const float* __restrict__ be_hh,
             float* __restrict__ out, int crows)
{
  int id = blockIdx.x * 256 + threadIdx.x;   // one 8-col unit
  if (id >= crows * 128) return;
  const int row = id >> 7;
  const int c0  = (id & 127) * 8;

  const float* __restrict__ st = stats + (size_t)row * 10;
  const float mu0 = st[0], mu1 = st[1], mu2 = st[2], mu3 = st[3], mu4 = st[4];
  const float r0 = st[5], r1 = st[6], r2 = st[7], r3 = st[8], r4 = st[9];

  const bf16_t* __restrict__ src = preLN + (size_t)row * NCOLS + c0;
  f32x8_t x_igr = cvt8(*(const bf16x8*)(src));
  f32x8_t x_igz = cvt8(*(const bf16x8*)(src + 1024));
  f32x8_t x_igg = cvt8(*(const bf16x8*)(src + 2048));
  f32x8_t x_ii  = cvt8(*(const bf16x8*)(src + 3072));
  f32x8_t x_ih  = cvt8(*(const bf16x8*)(src + 4096));
  f32x8_t x_hgr = cvt8(*(const bf16x8*)(src + 5120));
  f32x8_t x_hgz = cvt8(*(const bf16x8*)(src + 6144));
  f32x8_t x_hgg = cvt8(*(const bf16x8*)(src + 7168));
  f32x8_t x_hh  = cvt8(*(const bf16x8*)(src + 8192));

  f32x8_t pr = (x_igr - mu0) * r0 * ld8f(g_ig + c0)        + ld8f(be_ig + c0)
             + (x_hgr - mu3) * r3 * ld8f(g_hg + c0)        + ld8f(be_hg + c0);
  f32x8_t pz = (x_igz - mu0) * r0 * ld8f(g_ig + c0 + 1024) + ld8f(be_ig + c0 + 1024)
             + (x_hgz - mu3) * r3 * ld8f(g_hg + c0 + 1024) + ld8f(be_hg + c0 + 1024);
  f32x8_t pg = (x_igg - mu0) * r0 * ld8f(g_ig + c0 + 2048) + ld8f(be_ig + c0 + 2048)
             + (x_hgg - mu3) * r3 * ld8f(g_hg + c0 + 2048) + ld8f(be_hg + c0 + 2048);

  f32x8_t Hx = (x_ii - mu1) * r1 * ld8f(g_ii + c0) + ld8f(be_ii + c0);
  f32x8_t xh = (x_ih - mu2) * r2 * ld8f(g_ih + c0) + ld8f(be_ih + c0);
  f32x8_t hh = (x_hh - mu4) * r4 * ld8f(g_hh + c0) + ld8f(be_hh + c0);

  f32x8_t hv = ld8f(hidden + (size_t)row * 1024 + c0);

  f32x8_t o;
  #pragma unroll
  for (int i = 0; i < 8; ++i) {
    float rr = 1.f / (1.f + __expf(-pr[i]));
    float zz = 1.f / (1.f + __expf(-pz[i]));
    float gg = 1.f / (1.f + __expf(-pg[i]));
    float pre = (1.f - rr) * xh[i] + rr * hh[i];
    float hm  = 1.f - 2.f / (1.f + __expf(2.f * pre));   // tanh
    o[i] = ((1.f - zz) * hv[i] + zz * hm) * (1.f - gg) + gg * Hx[i];
  }
  float* __restrict__ dst = out + (size_t)row * 1024 + c0;
  *(float4*)dst       = *(float4*)&o;
  *((float4*)dst + 1) = *((float4*)&o + 1);
}

extern "C" void kernel_launch(void* const* d_in, const int* in_sizes, int n_in,
                              void* d_out, int out_size, void* d_ws, size_t ws_size,
                              hipStream_t stream) {
  const float* inp      = (const float*)d_in[0];
  const float* hidden   = (const float*)d_in[1];
  const float* W_i2gate = (const float*)d_in[2];
  const float* b_i2gate = (const float*)d_in[3];
  const float* W_h2gate = (const float*)d_in[4];
  const float* b_h2gate = (const float*)d_in[5];
  const float* W_i2i    = (const float*)d_in[6];
  const float* b_i2i    = (const float*)d_in[7];
  const float* W_i2h    = (const float*)d_in[8];
  const float* b_i2h    = (const float*)d_in[9];
  const float* W_h2h    = (const float*)d_in[10];
  const float* b_h2h    = (const float*)d_in[11];
  const float* g_ig  = (const float*)d_in[12];
  const float* be_ig = (const float*)d_in[13];
  const float* g_hg  = (const float*)d_in[14];
  const float* be_hg = (const float*)d_in[15];
  const float* g_ii  = (const float*)d_in[16];
  const float* be_ii = (const float*)d_in[17];
  const float* g_ih  = (const float*)d_in[18];
  const float* be_ih = (const float*)d_in[19];
  const float* g_hh  = (const float*)d_in[20];
  const float* be_hh = (const float*)d_in[21];
  float* out = (float*)d_out;

  const size_t WCAT_B  = (size_t)NCOLS * KDIM * 2;     // 18,874,368
  const size_t BCAT_B  = (size_t)NCOLS * 4;            // 36,864
  const size_t FIXED_B = WCAT_B + BCAT_B;
  // per-row: stats 40 + part1 576 + part2 576 + inpb 2048 + hidb 2048 + preLN 18432
  const size_t PER_ROW = 40 + 576 + 576 + 2048 + 2048 + 18432;   // 23,720

  if (ws_size < FIXED_B + PER_ROW * 256) return;       // visible fail, no OOB

  char* ws = (char*)d_ws;
  bf16_t* Wcat = (bf16_t*)ws;
  float*  bcat = (float*)(ws + WCAT_B);
  char*   dyn  = ws + FIXED_B;

  size_t max_rows = (ws_size - FIXED_B) / PER_ROW;
  int chunk = (int)((max_rows / 256) * 256);
  if (chunk > BATCH) chunk = BATCH;

  float*  stats = (float*)dyn;
  float*  part1 = (float*)(dyn + (size_t)chunk * 40);
  float*  part2 = (float*)(dyn + (size_t)chunk * (40 + 576));
  bf16_t* inpb  = (bf16_t*)(dyn + (size_t)chunk * (40 + 1152));
  bf16_t* hidb  = (bf16_t*)(dyn + (size_t)chunk * (40 + 1152 + 2048));
  bf16_t* preLN = (bf16_t*)(dyn + (size_t)chunk * (40 + 1152 + 4096));

  {
    int n4g = 3072 * 1024 / 4, n4s = 1024 * 1024 / 4;
    cast_f32_bf16<<<(n4g + 255) / 256, 256, 0, stream>>>(W_i2gate, Wcat, n4g);
    cast_f32_bf16<<<(n4s + 255) / 256, 256, 0, stream>>>(W_i2i, Wcat + 3072 * 1024, n4s);
    cast_f32_bf16<<<(n4s + 255) / 256, 256, 0, stream>>>(W_i2h, Wcat + 4096 * 1024, n4s);
    cast_f32_bf16<<<(n4g + 255) / 256, 256, 0, stream>>>(W_h2gate, Wcat + 5120 * 1024, n4g);
    cast_f32_bf16<<<(n4s + 255) / 256, 256, 0, stream>>>(W_h2h, Wcat + 8192 * 1024, n4s);
    concat_bias<<<(NCOLS + 255) / 256, 256, 0, stream>>>(b_i2gate, b_i2i, b_i2h,
                                                         b_h2gate, b_h2h, bcat);
  }

  for (int r0 = 0; r0 < BATCH; r0 += chunk) {
    int cr = BATCH - r0;
    if (cr > chunk) cr = chunk;
    int n4 = cr * KDIM / 4;
    cast_f32_bf16<<<(n4 + 255) / 256, 256, 0, stream>>>(inp + (size_t)r0 * KDIM, inpb, n4);
    cast_f32_bf16<<<(n4 + 255) / 256, 256, 0, stream>>>(hidden + (size_t)r0 * KDIM, hidb, n4);

    dim3 ggrid(cr / BM, NCOLS / BN);
    gemm_preln<<<ggrid, 256, 0, stream>>>(inpb, hidb, Wcat, bcat, preLN, part1, part2, cr);

    stat_reduce<<<(cr + 255) / 256, 256, 0, stream>>>(part1, part2, stats, cr);

    combine<<<(cr * 128 + 255) / 256, 256, 0, stream>>>(preLN, stats,
                                       hidden + (size_t)r0 * KDIM,
                                       g_ig, be_ig, g_hg, be_hg,
                                       g_ii, be_ii, g_ih, be_ih, g_hh, be_hh,
                                       out + (size_t)r0 * KDIM, cr);
  }
}

// Round 6
// 645.186 us; speedup vs baseline: 1.5958x; 1.2996x over previous
//
#include <hip/hip_runtime.h>

typedef __bf16 bf16_t;
typedef bf16_t bf16x8 __attribute__((ext_vector_type(8)));
typedef bf16_t bf16x4 __attribute__((ext_vector_type(4)));
typedef float f32x4 __attribute__((ext_vector_type(4)));

#define BATCH 16384
#define KDIM  1024
#define NCOLS 9216   // [0,3072) ig | [3072,4096) ii | [4096,5120) ih | [5120,8192) hg | [8192,9216) hh

#define BM 128
#define BN 128
#define BK 32

// ---------------- one-dispatch cast/concat: weights -> Wcat, biases -> bcat, acts -> bf16 ----------------
// unit = 4 consecutive floats. Ranges (units):
//   [0, 786432)          W_i2gate -> Wcat[0]
//   [786432, 1048576)    W_i2i    -> Wcat[3072*1024]
//   [1048576, 1310720)   W_i2h    -> Wcat[4096*1024]
//   [1310720, 2097152)   W_h2gate -> Wcat[5120*1024]
//   [2097152, 2359296)   W_h2h    -> Wcat[8192*1024]
//   [2359296, 2361600)   biases   -> bcat (float4)
//   [2361600, +nact)     inp      -> inpb
//   [.., +nact)          hidden   -> hidb
__global__ __launch_bounds__(256)
void cast_all(const float* __restrict__ Wig, const float* __restrict__ Wii,
              const float* __restrict__ Wih, const float* __restrict__ Whg,
              const float* __restrict__ Whh,
              const float* __restrict__ big, const float* __restrict__ bii,
              const float* __restrict__ bih, const float* __restrict__ bhg,
              const float* __restrict__ bhh,
              const float* __restrict__ inp, const float* __restrict__ hid,
              bf16_t* __restrict__ Wcat, float* __restrict__ bcat,
              bf16_t* __restrict__ inpb, bf16_t* __restrict__ hidb,
              int nact_units, int ntot)
{
  int u = blockIdx.x * 256 + threadIdx.x;
  if (u >= ntot) return;

  if (u < 2359296) {   // weights
    const float* src; int off;
    if      (u < 786432)  { src = Wig; off = u; }
    else if (u < 1048576) { src = Wii; off = u - 786432; }
    else if (u < 1310720) { src = Wih; off = u - 1048576; }
    else if (u < 2097152) { src = Whg; off = u - 1310720; }
    else                  { src = Whh; off = u - 2097152; }
    float4 v = reinterpret_cast<const float4*>(src)[off];
    bf16x4 o;
    o[0] = (bf16_t)v.x; o[1] = (bf16_t)v.y; o[2] = (bf16_t)v.z; o[3] = (bf16_t)v.w;
    reinterpret_cast<bf16x4*>(Wcat)[u] = o;
  } else if (u < 2361600) {  // biases
    int bu = u - 2359296;    // unit within 9216 floats
    int i = bu * 4;
    const float* src; int off;
    if      (i < 3072) { src = big; off = i; }
    else if (i < 4096) { src = bii; off = i - 3072; }
    else if (i < 5120) { src = bih; off = i - 4096; }
    else if (i < 8192) { src = bhg; off = i - 5120; }
    else               { src = bhh; off = i - 8192; }
    reinterpret_cast<float4*>(bcat)[bu] = *reinterpret_cast<const float4*>(src + off);
  } else {                    // activations
    int au = u - 2361600;
    const float* src; bf16_t* dst; int off;
    if (au < nact_units) { src = inp; dst = inpb; off = au; }
    else                 { src = hid; dst = hidb; off = au - nact_units; }
    float4 v = reinterpret_cast<const float4*>(src)[off];
    bf16x4 o;
    o[0] = (bf16_t)v.x; o[1] = (bf16_t)v.y; o[2] = (bf16_t)v.z; o[3] = (bf16_t)v.w;
    reinterpret_cast<bf16x4*>(dst)[off] = o;
  }
}

// fallback per-chunk act cast (only used if ws forces chunking)
__global__ __launch_bounds__(256)
void cast_acts(const float* __restrict__ inp, const float* __restrict__ hid,
               bf16_t* __restrict__ inpb, bf16_t* __restrict__ hidb, int n4) {
  int i = blockIdx.x * 256 + threadIdx.x;
  if (i >= 2 * n4) return;
  const float* src = (i < n4) ? inp : hid;
  bf16_t* dst = (i < n4) ? inpb : hidb;
  int off = (i < n4) ? i : i - n4;
  float4 v = reinterpret_cast<const float4*>(src)[off];
  bf16x4 o;
  o[0] = (bf16_t)v.x; o[1] = (bf16_t)v.y; o[2] = (bf16_t)v.z; o[3] = (bf16_t)v.w;
  reinterpret_cast<bf16x4*>(dst)[off] = o;
}

// ---------------- GEMM: exact R2 structure (measured 330 us, VGPR 68) ----------------
__global__ __launch_bounds__(256)
void gemm_preln(const bf16_t* __restrict__ inpb, const bf16_t* __restrict__ hidb,
                const bf16_t* __restrict__ Wcat, const float* __restrict__ bcat,
                bf16_t* __restrict__ preLN)
{
  __shared__ alignas(16) bf16_t As[2][BM * BK];
  __shared__ alignas(16) bf16_t Bs[2][BN * BK];
  const int tid  = threadIdx.x;
  const int wid  = tid >> 6;
  const int lane = tid & 63;
  const int row0 = blockIdx.x * BM;
  const int col0 = blockIdx.y * BN;
  const bf16_t* __restrict__ act = (col0 < 5120) ? inpb : hidb;
  const bf16_t* __restrict__ wgt = Wcat + (size_t)col0 * KDIM;

  f32x4 acc[4][4] = {};

  const int wr = wid >> 1, wc = wid & 1;
  const int fr = lane & 15;
  const int kg = lane >> 4;

  auto stage = [&](int buf, int kt) {
    const int k0 = kt * BK;
    #pragma unroll
    for (int c = 0; c < 2; ++c) {
      const int e = c * 2048 + tid * 8;
      const int r = e >> 5, kk = e & 31;
      const bf16_t* ga = act + (size_t)(row0 + r) * KDIM + (k0 + kk);
      const bf16_t* gb = wgt + (size_t)r * KDIM + (k0 + kk);
      __builtin_amdgcn_global_load_lds(
          (const __attribute__((address_space(1))) unsigned int*)ga,
          (__attribute__((address_space(3))) unsigned int*)&As[buf][c * 2048 + wid * 512],
          16, 0, 0);
      __builtin_amdgcn_global_load_lds(
          (const __attribute__((address_space(1))) unsigned int*)gb,
          (__attribute__((address_space(3))) unsigned int*)&Bs[buf][c * 2048 + wid * 512],
          16, 0, 0);
    }
  };

  auto compute = [&](int buf) {
    bf16x8 a[4], b[4];
    #pragma unroll
    for (int m = 0; m < 4; ++m)
      a[m] = *(const bf16x8*)&As[buf][(wr * 64 + m * 16 + fr) * BK + kg * 8];
    #pragma unroll
    for (int n = 0; n < 4; ++n)
      b[n] = *(const bf16x8*)&Bs[buf][(wc * 64 + n * 16 + fr) * BK + kg * 8];
    #pragma unroll
    for (int m = 0; m < 4; ++m)
      #pragma unroll
      for (int n = 0; n < 4; ++n)
        acc[m][n] = __builtin_amdgcn_mfma_f32_16x16x32_bf16(a[m], b[n], acc[m][n], 0, 0, 0);
  };

  stage(0, 0);
  __syncthreads();
  int cur = 0;
  const int NT = KDIM / BK;
  for (int t = 0; t < NT; ++t) {
    if (t + 1 < NT) stage(cur ^ 1, t + 1);
    compute(cur);
    __syncthreads();
    cur ^= 1;
  }

  const int orow = row0 + wr * 64;
  const int ocol = col0 + wc * 64;
  #pragma unroll
  for (int n = 0; n < 4; ++n) {
    const int col = ocol + n * 16 + fr;
    const float bias = bcat[col];
    #pragma unroll
    for (int m = 0; m < 4; ++m) {
      const int rbase = orow + m * 16 + kg * 4;
      #pragma unroll
      for (int j = 0; j < 4; ++j)
        preLN[(size_t)(rbase + j) * NCOLS + col] = (bf16_t)(acc[m][n][j] + bias);
    }
  }
}

// ---------------- fused LN + gates + combine: single-sweep stats (R3 version) ----------------
__global__ __launch_bounds__(256)
void ln_combine(const bf16_t* __restrict__ preLN, const float* __restrict__ hidden,
                const float* __restrict__ g_ig, const float* __restrict__ be_ig,
                const float* __restrict__ g_hg, const float* __restrict__ be_hg,
                const float* __restrict__ g_ii, const float* __restrict__ be_ii,
                const float* __restrict__ g_ih, const float* __restrict__ be_ih,
                const float* __restrict__ g_hh, const float* __restrict__ be_hh,
                float* __restrict__ out)
{
  __shared__ alignas(16) bf16_t rowbuf[NCOLS];
  __shared__ float wsum[4][10];
  __shared__ float stats[10];
  const int tid = threadIdx.x;
  const int wv  = tid >> 6;
  const int ln  = tid & 63;
  const size_t row = blockIdx.x;
  const bf16_t* __restrict__ src = preLN + row * NCOLS;

  // one sweep: global -> LDS, accumulate per-segment sums in regs.
  float s1[5] = {0.f, 0.f, 0.f, 0.f, 0.f};
  float s2[5] = {0.f, 0.f, 0.f, 0.f, 0.f};
  #pragma unroll
  for (int j = 0; j < 9; ++j) {
    const int idx = j * 1024 + tid * 4;
    bf16x4 v = *(const bf16x4*)&src[idx];
    *(bf16x4*)&rowbuf[idx] = v;
    const int sg = (j < 3) ? 0 : (j == 3) ? 1 : (j == 4) ? 2 : (j < 8) ? 3 : 4;
    const float f0 = (float)v[0], f1 = (float)v[1], f2 = (float)v[2], f3 = (float)v[3];
    s1[sg] += f0 + f1 + f2 + f3;
    s2[sg] += f0 * f0 + f1 * f1 + f2 * f2 + f3 * f3;
  }
  #pragma unroll
  for (int s = 0; s < 5; ++s)
    #pragma unroll
    for (int off = 32; off; off >>= 1) {
      s1[s] += __shfl_xor(s1[s], off);
      s2[s] += __shfl_xor(s2[s], off);
    }
  if (ln == 0) {
    #pragma unroll
    for (int s = 0; s < 5; ++s) { wsum[wv][s] = s1[s]; wsum[wv][5 + s] = s2[s]; }
  }
  __syncthreads();
  if (tid < 5) {
    const float n = (tid == 0 || tid == 3) ? 3072.f : 1024.f;
    float t1 = wsum[0][tid] + wsum[1][tid] + wsum[2][tid] + wsum[3][tid];
    float t2 = wsum[0][5 + tid] + wsum[1][5 + tid] + wsum[2][5 + tid] + wsum[3][5 + tid];
    float mu = t1 / n;
    float var = t2 / n - mu * mu;
    stats[tid] = mu;
    stats[5 + tid] = rsqrtf(var + 1e-5f);
  }
  __syncthreads();

  const float mu0 = stats[0], r0 = stats[5];
  const float mu1 = stats[1], r1 = stats[6];
  const float mu2 = stats[2], r2 = stats[7];
  const float mu3 = stats[3], r3 = stats[8];
  const float mu4 = stats[4], r4 = stats[9];
  const float* __restrict__ hrow = hidden + row * 1024;

  #pragma unroll
  for (int k = 0; k < 4; ++k) {
    const int c = tid + k * 256;
    float x_igr = (float)rowbuf[c];
    float x_igz = (float)rowbuf[c + 1024];
    float x_igg = (float)rowbuf[c + 2048];
    float x_ii  = (float)rowbuf[3072 + c];
    float x_ih  = (float)rowbuf[4096 + c];
    float x_hgr = (float)rowbuf[5120 + c];
    float x_hgz = (float)rowbuf[6144 + c];
    float x_hgg = (float)rowbuf[7168 + c];
    float x_hh  = (float)rowbuf[8192 + c];

    float pr = (x_igr - mu0) * r0 * g_ig[c]        + be_ig[c]
             + (x_hgr - mu3) * r3 * g_hg[c]        + be_hg[c];
    float pz = (x_igz - mu0) * r0 * g_ig[c + 1024] + be_ig[c + 1024]
             + (x_hgz - mu3) * r3 * g_hg[c + 1024] + be_hg[c + 1024];
    float pg = (x_igg - mu0) * r0 * g_ig[c + 2048] + be_ig[c + 2048]
             + (x_hgg - mu3) * r3 * g_hg[c + 2048] + be_hg[c + 2048];

    float rr = 1.f / (1.f + __expf(-pr));
    float zz = 1.f / (1.f + __expf(-pz));
    float gg = 1.f / (1.f + __expf(-pg));

    float Hx = (x_ii - mu1) * r1 * g_ii[c] + be_ii[c];
    float xh = (x_ih - mu2) * r2 * g_ih[c] + be_ih[c];
    float hh = (x_hh - mu4) * r4 * g_hh[c] + be_hh[c];

    float hm = tanhf((1.f - rr) * xh + rr * hh);
    float h  = hrow[c];
    out[row * 1024 + c] = ((1.f - zz) * h + zz * hm) * (1.f - gg) + gg * Hx;
  }
}

extern "C" void kernel_launch(void* const* d_in, const int* in_sizes, int n_in,
                              void* d_out, int out_size, void* d_ws, size_t ws_size,
                              hipStream_t stream) {
  const float* inp      = (const float*)d_in[0];
  const float* hidden   = (const float*)d_in[1];
  const float* W_i2gate = (const float*)d_in[2];
  const float* b_i2gate = (const float*)d_in[3];
  const float* W_h2gate = (const float*)d_in[4];
  const float* b_h2gate = (const float*)d_in[5];
  const float* W_i2i    = (const float*)d_in[6];
  const float* b_i2i    = (const float*)d_in[7];
  const float* W_i2h    = (const float*)d_in[8];
  const float* b_i2h    = (const float*)d_in[9];
  const float* W_h2h    = (const float*)d_in[10];
  const float* b_h2h    = (const float*)d_in[11];
  const float* g_ig  = (const float*)d_in[12];
  const float* be_ig = (const float*)d_in[13];
  const float* g_hg  = (const float*)d_in[14];
  const float* be_hg = (const float*)d_in[15];
  const float* g_ii  = (const float*)d_in[16];
  const float* be_ii = (const float*)d_in[17];
  const float* g_ih  = (const float*)d_in[18];
  const float* be_ih = (const float*)d_in[19];
  const float* g_hh  = (const float*)d_in[20];
  const float* be_hh = (const float*)d_in[21];
  float* out = (float*)d_out;

  const size_t WCAT_B  = (size_t)NCOLS * KDIM * 2;     // 18,874,368
  const size_t BCAT_B  = (size_t)NCOLS * 4;            // 36,864
  const size_t FIXED_B = WCAT_B + BCAT_B;
  const size_t PER_ROW = 2048 + 2048 + 18432;          // 22,528

  if (ws_size < FIXED_B + PER_ROW * 256) return;       // visible fail, no OOB

  char* ws = (char*)d_ws;
  bf16_t* Wcat = (bf16_t*)ws;
  float*  bcat = (float*)(ws + WCAT_B);
  char*   dyn  = ws + FIXED_B;

  size_t max_rows = (ws_size - FIXED_B) / PER_ROW;
  int chunk = (int)((max_rows / 256) * 256);
  if (chunk > BATCH) chunk = BATCH;

  bf16_t* inpb  = (bf16_t*)dyn;
  bf16_t* hidb  = (bf16_t*)(dyn + (size_t)chunk * 2048);
  bf16_t* preLN = (bf16_t*)(dyn + (size_t)chunk * 4096);

  if (chunk == BATCH) {
    // hot path: 3 dispatches total
    const int nact = BATCH * KDIM / 4;                 // 4,194,304
    const int ntot = 2361600 + 2 * nact;               // 10,750,208
    cast_all<<<(ntot + 255) / 256, 256, 0, stream>>>(
        W_i2gate, W_i2i, W_i2h, W_h2gate, W_h2h,
        b_i2gate, b_i2i, b_i2h, b_h2gate, b_h2h,
        inp, hidden, Wcat, bcat, inpb, hidb, nact, ntot);

    dim3 ggrid(BATCH / BM, NCOLS / BN);
    gemm_preln<<<ggrid, 256, 0, stream>>>(inpb, hidb, Wcat, bcat, preLN);

    ln_combine<<<BATCH, 256, 0, stream>>>(preLN, hidden,
                                          g_ig, be_ig, g_hg, be_hg,
                                          g_ii, be_ii, g_ih, be_ih, g_hh, be_hh,
                                          out);
  } else {
    // fallback: weights once, then chunked
    const int ntot_w = 2361600;
    cast_all<<<(ntot_w + 255) / 256, 256, 0, stream>>>(
        W_i2gate, W_i2i, W_i2h, W_h2gate, W_h2h,
        b_i2gate, b_i2i, b_i2h, b_h2gate, b_h2h,
        nullptr, nullptr, Wcat, bcat, nullptr, nullptr, 0, ntot_w);

    for (int r0 = 0; r0 < BATCH; r0 += chunk) {
      int cr = BATCH - r0;
      if (cr > chunk) cr = chunk;
      int n4 = cr * KDIM / 4;
      cast_acts<<<(2 * n4 + 255) / 256, 256, 0, stream>>>(
          inp + (size_t)r0 * KDIM, hidden + (size_t)r0 * KDIM, inpb, hidb, n4);

      dim3 ggrid(cr / BM, NCOLS / BN);
      gemm_preln<<<ggrid, 256, 0, stream>>>(inpb, hidb, Wcat, bcat, preLN);

      ln_combine<<<cr, 256, 0, stream>>>(preLN, hidden + (size_t)r0 * KDIM,
                                         g_ig, be_ig, g_hg, be_hg,
                                         g_ii, be_ii, g_ih, be_ih, g_hh, be_hh,
                                         out + (size_t)r0 * KDIM);
    }
  }
}